// Round 3
// baseline (25422.626 us; speedup 1.0000x reference)
//
#include <hip/hip_runtime.h>

#define NWG   256
#define NTHR  256
#define TT    2048
#define HH    2048
#define EE    1024

__device__ __forceinline__ int imin(int a, int b){ return a < b ? a : b; }

__device__ __forceinline__ float wred(float v){
  v += __shfl_xor(v, 1, 64);
  v += __shfl_xor(v, 2, 64);
  v += __shfl_xor(v, 4, 64);
  v += __shfl_xor(v, 8, 64);
  v += __shfl_xor(v, 16, 64);
  v += __shfl_xor(v, 32, 64);
  return v;
}

__device__ __forceinline__ float sigm(float x){ return 1.0f / (1.0f + __expf(-x)); }

extern "C" __global__ void __launch_bounds__(NTHR, 1)
lstm_seq_kernel(const float* __restrict__ h0, const float* __restrict__ c0,
                const float* __restrict__ gt, const int* __restrict__ ugt,
                const float* __restrict__ W_emb, const float* __restrict__ b_emb,
                const float* __restrict__ W_ih, const float* __restrict__ b_ih,
                const float* __restrict__ W_hh, const float* __restrict__ b_hh,
                const float* __restrict__ W_out, const float* __restrict__ b_out,
                float* __restrict__ out, float* __restrict__ hbuf, int* __restrict__ flags)
{
  const int wgid = blockIdx.x;    // 0..255, owns hidden units [8*wgid, 8*wgid+8)
  const int tid  = threadIdx.x;
  const int gw   = tid >> 6;      // wave index == gate index (i,f,g,o)
  const int l    = tid & 63;
  const int j0   = wgid * 8;

  __shared__ float h_lds[HH];
  __shared__ float gates_lds[4][8];

  // ---------- setup: W_hh slice into fp32 registers ----------
  // wave gw, row u -> global row 2048*gw + j0 + u ; lane l holds k = 2l+128i (+1)
  float2 whh[8][16];
  #pragma unroll
  for (int u = 0; u < 8; ++u){
    const float* rp = W_hh + (size_t)(2048*gw + j0 + u) * HH;
    #pragma unroll
    for (int i = 0; i < 16; ++i)
      whh[u][i] = *(const float2*)(rp + 2*l + 128*i);
  }
  // W_out rows (each wave keeps a copy -> redundant raw, no extra barrier)
  float2 wo0[16], wo1[16];
  #pragma unroll
  for (int i = 0; i < 16; ++i){
    wo0[i] = *(const float2*)(W_out + 2*l + 128*i);
    wo1[i] = *(const float2*)(W_out + HH + 2*l + 128*i);
  }
  const float bo0 = b_out[0], bo1 = b_out[1];

  // ---------- setup: W_ihe = W_ih@W_emb and base = W_ih@b_emb + b_ih + b_hh ----------
  float aE0[8], aE1[8], aB[8];
  #pragma unroll
  for (int u = 0; u < 8; ++u){ aE0[u] = 0.f; aE1[u] = 0.f; aB[u] = 0.f; }
  for (int i = 0; i < 16; ++i){
    const int k = l + 64*i;
    const float2 we = *(const float2*)(W_emb + 2*k);
    const float be = b_emb[k];
    #pragma unroll
    for (int u = 0; u < 8; ++u){
      const float wv = W_ih[(size_t)(2048*gw + j0 + u)*EE + k];
      aE0[u] = fmaf(wv, we.x, aE0[u]);
      aE1[u] = fmaf(wv, we.y, aE1[u]);
      aB[u]  = fmaf(wv, be,  aB[u]);
    }
  }
  float myE0 = 0.f, myE1 = 0.f, myB = 0.f;
  #pragma unroll
  for (int u = 0; u < 8; ++u){
    const float e0 = wred(aE0[u]);
    const float e1 = wred(aE1[u]);
    const float bb = wred(aB[u]);
    if (l == u){
      const int r = 2048*gw + j0 + u;
      myE0 = e0; myE1 = e1; myB = bb + b_ih[r] + b_hh[r];
    }
  }

  float c_state = (gw == 0 && l < 8) ? c0[j0 + l] : 0.f;

  for (int t = 0; t < TT; ++t){
    // ---- global barrier: wait until all WGs posted step t (flag value t) ----
    if (t > 0 && gw == 0){
      int cnt = 0;
      for (;;){
        const int f0 = __hip_atomic_load(flags + l,       __ATOMIC_RELAXED, __HIP_MEMORY_SCOPE_AGENT);
        const int f1 = __hip_atomic_load(flags + l + 64,  __ATOMIC_RELAXED, __HIP_MEMORY_SCOPE_AGENT);
        const int f2 = __hip_atomic_load(flags + l + 128, __ATOMIC_RELAXED, __HIP_MEMORY_SCOPE_AGENT);
        const int f3 = __hip_atomic_load(flags + l + 192, __ATOMIC_RELAXED, __HIP_MEMORY_SCOPE_AGENT);
        if (imin(imin(f0,f1), imin(f2,f3)) >= t) break;
        if (++cnt > 65536) break;            // anti-hang guard
        __builtin_amdgcn_s_sleep(1);
      }
      __builtin_amdgcn_fence(__ATOMIC_ACQUIRE, "agent");
    }
    __syncthreads();

    // ---- stage h_{t-1} into LDS (double-buffered global h) ----
    const float* hsrc = (t == 0) ? h0 : (hbuf + ((t-1)&1)*HH);
    #pragma unroll
    for (int k = 0; k < 8; ++k)
      h_lds[tid + 256*k] = __hip_atomic_load(hsrc + tid + 256*k, __ATOMIC_RELAXED, __HIP_MEMORY_SCOPE_AGENT);
    __syncthreads();

    // ---- dot products: 8 gate rows (this wave's gate) + redundant W_out rows ----
    float ga[8];
    #pragma unroll
    for (int u = 0; u < 8; ++u) ga[u] = 0.f;
    float r0 = 0.f, r1 = 0.f;
    #pragma unroll
    for (int i = 0; i < 16; ++i){
      const float2 hv = *(const float2*)(h_lds + 2*l + 128*i);
      r0 = fmaf(wo0[i].x, hv.x, r0); r0 = fmaf(wo0[i].y, hv.y, r0);
      r1 = fmaf(wo1[i].x, hv.x, r1); r1 = fmaf(wo1[i].y, hv.y, r1);
      #pragma unroll
      for (int u = 0; u < 8; ++u){
        ga[u] = fmaf(whh[u][i].x, hv.x, ga[u]);
        ga[u] = fmaf(whh[u][i].y, hv.y, ga[u]);
      }
    }
    #pragma unroll
    for (int u = 0; u < 8; ++u) ga[u] = wred(ga[u]);
    r0 = wred(r0); r1 = wred(r1);

    // ---- raw_{t-1}, teacher forcing (loss handled by separate kernel) ----
    const float raw0 = r0 + bo0, raw1 = r1 + bo1;
    float n0, n1;
    if (t == 0){ n0 = 1.f; n1 = 1.f; }     // x0 = W_emb@ones(2)+b_emb  <=> nxt=(1,1)
    else {
      const float g0 = gt[2*(t-1)], g1 = gt[2*(t-1)+1];
      const int u = ugt[t-1];
      if (wgid == 0 && tid == 0){
        out[2*(t-1)]   = raw0;
        out[2*(t-1)+1] = raw1;
      }
      n0 = (u == 1) ? g0 : raw0;
      n1 = (u == 1) ? g1 : raw1;
    }

    // ---- finalize this wave's gate values for its 8 units ----
    if (l < 8){
      float gate = ga[0];
      #pragma unroll
      for (int u = 1; u < 8; ++u) if (l == u) gate = ga[u];
      gate += fmaf(myE0, n0, fmaf(myE1, n1, myB));
      gates_lds[gw][l] = gate;
    }
    __syncthreads();

    // ---- LSTM cell update (wave0 lanes 0..7) + publish h_new + flag ----
    if (gw == 0 && l < 8){
      const float gi = gates_lds[0][l], gf = gates_lds[1][l];
      const float gg = gates_lds[2][l], go = gates_lds[3][l];
      const float cn = sigm(gf)*c_state + sigm(gi)*tanhf(gg);
      const float hn = sigm(go)*tanhf(cn);
      c_state = cn;
      __hip_atomic_store(hbuf + (t&1)*HH + j0 + l, hn, __ATOMIC_RELAXED, __HIP_MEMORY_SCOPE_AGENT);
    }
    if (gw == 0){
      asm volatile("s_waitcnt vmcnt(0)" ::: "memory");   // h stores at coherence point
      if (l == 0)
        __hip_atomic_store(flags + wgid, t + 1, __ATOMIC_RELEASE, __HIP_MEMORY_SCOPE_AGENT);
    }
  }

  if (wgid != 0) return;

  // ---------- epilogue (WG0): raw for the final step ----------
  if (gw == 0){
    int cnt = 0;
    for (;;){
      const int f0 = __hip_atomic_load(flags + l,       __ATOMIC_RELAXED, __HIP_MEMORY_SCOPE_AGENT);
      const int f1 = __hip_atomic_load(flags + l + 64,  __ATOMIC_RELAXED, __HIP_MEMORY_SCOPE_AGENT);
      const int f2 = __hip_atomic_load(flags + l + 128, __ATOMIC_RELAXED, __HIP_MEMORY_SCOPE_AGENT);
      const int f3 = __hip_atomic_load(flags + l + 192, __ATOMIC_RELAXED, __HIP_MEMORY_SCOPE_AGENT);
      if (imin(imin(f0,f1), imin(f2,f3)) >= TT) break;
      if (++cnt > 65536) break;
      __builtin_amdgcn_s_sleep(1);
    }
    __builtin_amdgcn_fence(__ATOMIC_ACQUIRE, "agent");
  }
  __syncthreads();
  #pragma unroll
  for (int k = 0; k < 8; ++k)
    h_lds[tid + 256*k] = __hip_atomic_load(hbuf + ((TT-1)&1)*HH + tid + 256*k, __ATOMIC_RELAXED, __HIP_MEMORY_SCOPE_AGENT);
  __syncthreads();
  if (gw == 0){
    float r0 = 0.f, r1 = 0.f;
    #pragma unroll
    for (int i = 0; i < 16; ++i){
      const float2 hv = *(const float2*)(h_lds + 2*l + 128*i);
      r0 = fmaf(wo0[i].x, hv.x, r0); r0 = fmaf(wo0[i].y, hv.y, r0);
      r1 = fmaf(wo1[i].x, hv.x, r1); r1 = fmaf(wo1[i].y, hv.y, r1);
    }
    r0 = wred(r0); r1 = wred(r1);
    if (l == 0){
      out[2*(TT-1)]   = r0 + bo0;
      out[2*(TT-1)+1] = r1 + bo1;
    }
  }
}

// Loss = pure function of (preds, gt). Preds are already validated by output 0,
// so computing the loss from them decouples the scalar from the big kernel.
extern "C" __global__ void loss_kernel(const float* __restrict__ preds,
                                       const float* __restrict__ gt,
                                       float* __restrict__ loss_out)
{
  const int tid = threadIdx.x;   // 256 threads, 8 steps each
  float acc = 0.f;
  #pragma unroll
  for (int s = 0; s < 8; ++s){
    const int t = tid + 256*s;
    const float d0 = preds[2*t]   - gt[2*t];
    const float d1 = preds[2*t+1] - gt[2*t+1];
    acc += 0.5f*(d0*d0 + d1*d1);
  }
  acc = wred(acc);
  __shared__ float ws[4];
  if ((tid & 63) == 0) ws[tid >> 6] = acc;
  __syncthreads();
  if (tid == 0) loss_out[0] = ws[0] + ws[1] + ws[2] + ws[3];
}

extern "C" void kernel_launch(void* const* d_in, const int* in_sizes, int n_in,
                              void* d_out, int out_size, void* d_ws, size_t ws_size,
                              hipStream_t stream)
{
  (void)in_sizes; (void)n_in; (void)out_size; (void)ws_size;
  const float* h0    = (const float*)d_in[0];
  const float* c0    = (const float*)d_in[1];
  const float* gt    = (const float*)d_in[2];
  const int*   ugt   = (const int*)  d_in[3];
  const float* W_emb = (const float*)d_in[4];
  const float* b_emb = (const float*)d_in[5];
  const float* W_ih  = (const float*)d_in[6];
  const float* b_ih  = (const float*)d_in[7];
  const float* W_hh  = (const float*)d_in[8];
  const float* b_hh  = (const float*)d_in[9];
  const float* W_out = (const float*)d_in[10];
  const float* b_out = (const float*)d_in[11];
  float* out  = (float*)d_out;
  float* hbuf = (float*)d_ws;                                // 2 x 2048 floats
  int*   flags = (int*)((char*)d_ws + 2*HH*sizeof(float));   // 256 ints

  void* args[] = { &h0, &c0, &gt, &ugt, &W_emb, &b_emb, &W_ih, &b_ih,
                   &W_hh, &b_hh, &W_out, &b_out, &out, &hbuf, &flags };
  hipLaunchCooperativeKernel((const void*)lstm_seq_kernel,
                             dim3(NWG), dim3(NTHR), args, 0, stream);

  loss_kernel<<<dim3(1), dim3(NTHR), 0, stream>>>(out, gt, out + 2*TT);
}

// Round 4
// 16395.699 us; speedup vs baseline: 1.5506x; 1.5506x over previous
//
#include <hip/hip_runtime.h>

#define NWG   256
#define NTHR  256
#define TT    2048
#define HH    2048
#define EE    1024

__device__ __forceinline__ int imin(int a, int b){ return a < b ? a : b; }

__device__ __forceinline__ float wred(float v){
  v += __shfl_xor(v, 1, 64);
  v += __shfl_xor(v, 2, 64);
  v += __shfl_xor(v, 4, 64);
  v += __shfl_xor(v, 8, 64);
  v += __shfl_xor(v, 16, 64);
  v += __shfl_xor(v, 32, 64);
  return v;
}

__device__ __forceinline__ float sigm(float x){ return 1.0f / (1.0f + __expf(-x)); }

extern "C" __global__ void __launch_bounds__(NTHR, 1)
lstm_seq_kernel(const float* __restrict__ h0, const float* __restrict__ c0,
                const float* __restrict__ gt, const int* __restrict__ ugt,
                const float* __restrict__ W_emb, const float* __restrict__ b_emb,
                const float* __restrict__ W_ih, const float* __restrict__ b_ih,
                const float* __restrict__ W_hh, const float* __restrict__ b_hh,
                const float* __restrict__ W_out, const float* __restrict__ b_out,
                float* __restrict__ out, float* __restrict__ hbuf, int* __restrict__ flags)
{
  const int wgid = blockIdx.x;    // 0..255, owns hidden units [8*wgid, 8*wgid+8)
  const int tid  = threadIdx.x;
  const int gw   = tid >> 6;      // wave index == gate index (i,f,g,o)
  const int l    = tid & 63;
  const int j0   = wgid * 8;

  __shared__ float h_lds[HH];
  __shared__ float gates_lds[4][8];

  // ---------- setup: W_hh slice into fp32 registers ----------
  // wave gw, row u -> global row 2048*gw + j0 + u ; lane l holds k = 2l+128i (+1)
  float2 whh[8][16];
  #pragma unroll
  for (int u = 0; u < 8; ++u){
    const float* rp = W_hh + (size_t)(2048*gw + j0 + u) * HH;
    #pragma unroll
    for (int i = 0; i < 16; ++i)
      whh[u][i] = *(const float2*)(rp + 2*l + 128*i);
  }
  // W_out rows (each wave keeps a copy -> redundant raw, no extra barrier)
  float2 wo0[16], wo1[16];
  #pragma unroll
  for (int i = 0; i < 16; ++i){
    wo0[i] = *(const float2*)(W_out + 2*l + 128*i);
    wo1[i] = *(const float2*)(W_out + HH + 2*l + 128*i);
  }
  const float bo0 = b_out[0], bo1 = b_out[1];

  // ---------- setup: W_ihe = W_ih@W_emb and base = W_ih@b_emb + b_ih + b_hh ----------
  float aE0[8], aE1[8], aB[8];
  #pragma unroll
  for (int u = 0; u < 8; ++u){ aE0[u] = 0.f; aE1[u] = 0.f; aB[u] = 0.f; }
  for (int i = 0; i < 16; ++i){
    const int k = l + 64*i;
    const float2 we = *(const float2*)(W_emb + 2*k);
    const float be = b_emb[k];
    #pragma unroll
    for (int u = 0; u < 8; ++u){
      const float wv = W_ih[(size_t)(2048*gw + j0 + u)*EE + k];
      aE0[u] = fmaf(wv, we.x, aE0[u]);
      aE1[u] = fmaf(wv, we.y, aE1[u]);
      aB[u]  = fmaf(wv, be,  aB[u]);
    }
  }
  float myE0 = 0.f, myE1 = 0.f, myB = 0.f;
  #pragma unroll
  for (int u = 0; u < 8; ++u){
    const float e0 = wred(aE0[u]);
    const float e1 = wred(aE1[u]);
    const float bb = wred(aB[u]);
    if (l == u){
      const int r = 2048*gw + j0 + u;
      myE0 = e0; myE1 = e1; myB = bb + b_ih[r] + b_hh[r];
    }
  }

  float c_state = (gw == 0 && l < 8) ? c0[j0 + l] : 0.f;

  for (int t = 0; t < TT; ++t){
    // ---- hoist gt/ugt for this step: normal cached loads, overlap the poll ----
    float g0 = 0.f, g1 = 0.f; int ug = 0;
    if (t > 0){
      g0 = gt[2*(t-1)]; g1 = gt[2*(t-1)+1]; ug = ugt[t-1];
    }

    // ---- global barrier: wait until all WGs posted step t (flag value t) ----
    // No acquire FENCE needed: all cross-WG data (h, flags) moves via agent-scope
    // relaxed atomics (sc1, LLC-direct). Producer orders h-before-flag with
    // vmcnt(0); consumer's h loads issue after the dependent poll branch, so LLC
    // monotonicity guarantees freshness. Only compiler reordering must be blocked.
    if (t > 0 && gw == 0){
      int cnt = 0;
      for (;;){
        const int f0 = __hip_atomic_load(flags + l,       __ATOMIC_RELAXED, __HIP_MEMORY_SCOPE_AGENT);
        const int f1 = __hip_atomic_load(flags + l + 64,  __ATOMIC_RELAXED, __HIP_MEMORY_SCOPE_AGENT);
        const int f2 = __hip_atomic_load(flags + l + 128, __ATOMIC_RELAXED, __HIP_MEMORY_SCOPE_AGENT);
        const int f3 = __hip_atomic_load(flags + l + 192, __ATOMIC_RELAXED, __HIP_MEMORY_SCOPE_AGENT);
        if (imin(imin(f0,f1), imin(f2,f3)) >= t) break;
        if (++cnt > 65536) break;            // anti-hang guard
        __builtin_amdgcn_s_sleep(1);
      }
      asm volatile("" ::: "memory");         // compiler-only ordering
    }
    __syncthreads();

    // ---- stage h_{t-1} into LDS (double-buffered global h) ----
    const float* hsrc = (t == 0) ? h0 : (hbuf + ((t-1)&1)*HH);
    #pragma unroll
    for (int k = 0; k < 8; ++k)
      h_lds[tid + 256*k] = __hip_atomic_load(hsrc + tid + 256*k, __ATOMIC_RELAXED, __HIP_MEMORY_SCOPE_AGENT);
    __syncthreads();

    // ---- dot products: 8 gate rows (this wave's gate) + redundant W_out rows ----
    float ga[8];
    #pragma unroll
    for (int u = 0; u < 8; ++u) ga[u] = 0.f;
    float r0 = 0.f, r1 = 0.f;
    #pragma unroll
    for (int i = 0; i < 16; ++i){
      const float2 hv = *(const float2*)(h_lds + 2*l + 128*i);
      r0 = fmaf(wo0[i].x, hv.x, r0); r0 = fmaf(wo0[i].y, hv.y, r0);
      r1 = fmaf(wo1[i].x, hv.x, r1); r1 = fmaf(wo1[i].y, hv.y, r1);
      #pragma unroll
      for (int u = 0; u < 8; ++u){
        ga[u] = fmaf(whh[u][i].x, hv.x, ga[u]);
        ga[u] = fmaf(whh[u][i].y, hv.y, ga[u]);
      }
    }
    #pragma unroll
    for (int u = 0; u < 8; ++u) ga[u] = wred(ga[u]);
    r0 = wred(r0); r1 = wred(r1);

    // ---- raw_{t-1}, teacher forcing (loss handled by separate kernel) ----
    const float raw0 = r0 + bo0, raw1 = r1 + bo1;
    float n0, n1;
    if (t == 0){ n0 = 1.f; n1 = 1.f; }     // x0 = W_emb@ones(2)+b_emb  <=> nxt=(1,1)
    else {
      if (wgid == 0 && tid == 0){
        out[2*(t-1)]   = raw0;
        out[2*(t-1)+1] = raw1;
      }
      n0 = (ug == 1) ? g0 : raw0;
      n1 = (ug == 1) ? g1 : raw1;
    }

    // ---- finalize this wave's gate values for its 8 units ----
    if (l < 8){
      float gate = ga[0];
      #pragma unroll
      for (int u = 1; u < 8; ++u) if (l == u) gate = ga[u];
      gate += fmaf(myE0, n0, fmaf(myE1, n1, myB));
      gates_lds[gw][l] = gate;
    }
    __syncthreads();

    // ---- LSTM cell update (wave0 lanes 0..7) + publish h_new + flag ----
    if (gw == 0 && l < 8){
      const float gi = gates_lds[0][l], gf = gates_lds[1][l];
      const float gg = gates_lds[2][l], go = gates_lds[3][l];
      const float cn = sigm(gf)*c_state + sigm(gi)*tanhf(gg);
      const float hn = sigm(go)*tanhf(cn);
      c_state = cn;
      __hip_atomic_store(hbuf + (t&1)*HH + j0 + l, hn, __ATOMIC_RELAXED, __HIP_MEMORY_SCOPE_AGENT);
    }
    if (gw == 0){
      asm volatile("s_waitcnt vmcnt(0)" ::: "memory");   // h stores at coherence point
      if (l == 0)
        __hip_atomic_store(flags + wgid, t + 1, __ATOMIC_RELAXED, __HIP_MEMORY_SCOPE_AGENT);
    }
  }

  if (wgid != 0) return;

  // ---------- epilogue (WG0): raw for the final step ----------
  if (gw == 0){
    int cnt = 0;
    for (;;){
      const int f0 = __hip_atomic_load(flags + l,       __ATOMIC_RELAXED, __HIP_MEMORY_SCOPE_AGENT);
      const int f1 = __hip_atomic_load(flags + l + 64,  __ATOMIC_RELAXED, __HIP_MEMORY_SCOPE_AGENT);
      const int f2 = __hip_atomic_load(flags + l + 128, __ATOMIC_RELAXED, __HIP_MEMORY_SCOPE_AGENT);
      const int f3 = __hip_atomic_load(flags + l + 192, __ATOMIC_RELAXED, __HIP_MEMORY_SCOPE_AGENT);
      if (imin(imin(f0,f1), imin(f2,f3)) >= TT) break;
      if (++cnt > 65536) break;
      __builtin_amdgcn_s_sleep(1);
    }
    asm volatile("" ::: "memory");
  }
  __syncthreads();
  #pragma unroll
  for (int k = 0; k < 8; ++k)
    h_lds[tid + 256*k] = __hip_atomic_load(hbuf + ((TT-1)&1)*HH + tid + 256*k, __ATOMIC_RELAXED, __HIP_MEMORY_SCOPE_AGENT);
  __syncthreads();
  if (gw == 0){
    float r0 = 0.f, r1 = 0.f;
    #pragma unroll
    for (int i = 0; i < 16; ++i){
      const float2 hv = *(const float2*)(h_lds + 2*l + 128*i);
      r0 = fmaf(wo0[i].x, hv.x, r0); r0 = fmaf(wo0[i].y, hv.y, r0);
      r1 = fmaf(wo1[i].x, hv.x, r1); r1 = fmaf(wo1[i].y, hv.y, r1);
    }
    r0 = wred(r0); r1 = wred(r1);
    if (l == 0){
      out[2*(TT-1)]   = r0 + bo0;
      out[2*(TT-1)+1] = r1 + bo1;
    }
  }
}

// Loss = pure function of (preds, gt). Preds are already validated by output 0,
// so computing the loss from them decouples the scalar from the big kernel.
extern "C" __global__ void loss_kernel(const float* __restrict__ preds,
                                       const float* __restrict__ gt,
                                       float* __restrict__ loss_out)
{
  const int tid = threadIdx.x;   // 256 threads, 8 steps each
  float acc = 0.f;
  #pragma unroll
  for (int s = 0; s < 8; ++s){
    const int t = tid + 256*s;
    const float d0 = preds[2*t]   - gt[2*t];
    const float d1 = preds[2*t+1] - gt[2*t+1];
    acc += 0.5f*(d0*d0 + d1*d1);
  }
  acc = wred(acc);
  __shared__ float ws[4];
  if ((tid & 63) == 0) ws[tid >> 6] = acc;
  __syncthreads();
  if (tid == 0) loss_out[0] = ws[0] + ws[1] + ws[2] + ws[3];
}

extern "C" void kernel_launch(void* const* d_in, const int* in_sizes, int n_in,
                              void* d_out, int out_size, void* d_ws, size_t ws_size,
                              hipStream_t stream)
{
  (void)in_sizes; (void)n_in; (void)out_size; (void)ws_size;
  const float* h0    = (const float*)d_in[0];
  const float* c0    = (const float*)d_in[1];
  const float* gt    = (const float*)d_in[2];
  const int*   ugt   = (const int*)  d_in[3];
  const float* W_emb = (const float*)d_in[4];
  const float* b_emb = (const float*)d_in[5];
  const float* W_ih  = (const float*)d_in[6];
  const float* b_ih  = (const float*)d_in[7];
  const float* W_hh  = (const float*)d_in[8];
  const float* b_hh  = (const float*)d_in[9];
  const float* W_out = (const float*)d_in[10];
  const float* b_out = (const float*)d_in[11];
  float* out  = (float*)d_out;
  float* hbuf = (float*)d_ws;                                // 2 x 2048 floats
  int*   flags = (int*)((char*)d_ws + 2*HH*sizeof(float));   // 256 ints

  void* args[] = { &h0, &c0, &gt, &ugt, &W_emb, &b_emb, &W_ih, &b_ih,
                   &W_hh, &b_hh, &W_out, &b_out, &out, &hbuf, &flags };
  hipLaunchCooperativeKernel((const void*)lstm_seq_kernel,
                             dim3(NWG), dim3(NTHR), args, 0, stream);

  loss_kernel<<<dim3(1), dim3(NTHR), 0, stream>>>(out, gt, out + 2*TT);
}

// Round 8
// 9555.697 us; speedup vs baseline: 2.6605x; 1.7158x over previous
//
#include <hip/hip_runtime.h>

#define NWG   256
#define NTHR  256
#define TT    2048
#define HH    2048
#define EE    1024

__device__ __forceinline__ float wred(float v){
  v += __shfl_xor(v, 1, 64);
  v += __shfl_xor(v, 2, 64);
  v += __shfl_xor(v, 4, 64);
  v += __shfl_xor(v, 8, 64);
  v += __shfl_xor(v, 16, 64);
  v += __shfl_xor(v, 32, 64);
  return v;
}

__device__ __forceinline__ float sigm(float x){ return 1.0f / (1.0f + __expf(-x)); }

extern "C" __global__ void __launch_bounds__(NTHR, 1)
lstm_seq_kernel(const float* __restrict__ h0, const float* __restrict__ c0,
                const float* __restrict__ gt, const int* __restrict__ ugt,
                const float* __restrict__ W_emb, const float* __restrict__ b_emb,
                const float* __restrict__ W_ih, const float* __restrict__ b_ih,
                const float* __restrict__ W_hh, const float* __restrict__ b_hh,
                const float* __restrict__ W_out, const float* __restrict__ b_out,
                float* __restrict__ out, unsigned long long* __restrict__ hbuf)
{
  const int wgid = blockIdx.x;    // 0..255, owns hidden units [8*wgid, 8*wgid+8)
  const int tid  = threadIdx.x;
  const int gw   = tid >> 6;      // wave index == gate index (i,f,g,o)
  const int l    = tid & 63;
  const int j0   = wgid * 8;

  __shared__ float h_lds[HH];
  __shared__ float gates_lds[4][8];

  // ---------- setup: W_hh slice into fp32 registers ----------
  // wave gw, row u -> global row 2048*gw + j0 + u ; lane l holds k = 2l+128i (+1)
  float2 whh[8][16];
  #pragma unroll
  for (int u = 0; u < 8; ++u){
    const float* rp = W_hh + (size_t)(2048*gw + j0 + u) * HH;
    #pragma unroll
    for (int i = 0; i < 16; ++i)
      whh[u][i] = *(const float2*)(rp + 2*l + 128*i);
  }
  // W_out rows (each wave keeps a copy -> redundant raw, no extra barrier)
  float2 wo0[16], wo1[16];
  #pragma unroll
  for (int i = 0; i < 16; ++i){
    wo0[i] = *(const float2*)(W_out + 2*l + 128*i);
    wo1[i] = *(const float2*)(W_out + HH + 2*l + 128*i);
  }
  const float bo0 = b_out[0], bo1 = b_out[1];

  // ---------- setup: W_ihe = W_ih@W_emb and base = W_ih@b_emb + b_ih + b_hh ----------
  float aE0[8], aE1[8], aB[8];
  #pragma unroll
  for (int u = 0; u < 8; ++u){ aE0[u] = 0.f; aE1[u] = 0.f; aB[u] = 0.f; }
  for (int i = 0; i < 16; ++i){
    const int k = l + 64*i;
    const float2 we = *(const float2*)(W_emb + 2*k);
    const float be = b_emb[k];
    #pragma unroll
    for (int u = 0; u < 8; ++u){
      const float wv = W_ih[(size_t)(2048*gw + j0 + u)*EE + k];
      aE0[u] = fmaf(wv, we.x, aE0[u]);
      aE1[u] = fmaf(wv, we.y, aE1[u]);
      aB[u]  = fmaf(wv, be,  aB[u]);
    }
  }
  float myE0 = 0.f, myE1 = 0.f, myB = 0.f;
  #pragma unroll
  for (int u = 0; u < 8; ++u){
    const float e0 = wred(aE0[u]);
    const float e1 = wred(aE1[u]);
    const float bb = wred(aB[u]);
    if (l == u){
      const int r = 2048*gw + j0 + u;
      myE0 = e0; myE1 = e1; myB = bb + b_ih[r] + b_hh[r];
    }
  }

  float c_state = (gw == 0 && l < 8) ? c0[j0 + l] : 0.f;

  for (int t = 0; t < TT; ++t){
    // ---- hoist gt/ugt for this step (cached loads, overlap the poll) ----
    float g0 = 0.f, g1 = 0.f; int ug = 0;
    if (t > 0){
      g0 = gt[2*(t-1)]; g1 = gt[2*(t-1)+1]; ug = ugt[t-1];
    }

    // ---- stage h_{t-1} into LDS. Tagged-entry protocol: entry = (tag<<32)|bits,
    // tag==t marks h_{t-1}. Data IS the flag: one LLC trip, no fence, no vmcnt.
    // Each wave polls its quarter (8 entries/lane, batched loads).
    const int e0i = (gw << 9) + l;              // gw*512 + l
    if (t == 0){
      #pragma unroll
      for (int i = 0; i < 8; ++i)
        h_lds[e0i + (i<<6)] = h0[e0i + (i<<6)];
    } else {
      const unsigned long long* bp = hbuf + ((t-1)&1)*HH + e0i;
      const unsigned tagexp = (unsigned)t;
      unsigned fresh = 0; int rounds = 0;
      while (fresh != 0xFFu){
        unsigned long long v[8];
        #pragma unroll
        for (int i = 0; i < 8; ++i)
          v[i] = __hip_atomic_load(bp + (i<<6), __ATOMIC_RELAXED, __HIP_MEMORY_SCOPE_AGENT);
        #pragma unroll
        for (int i = 0; i < 8; ++i){
          if (!(fresh & (1u<<i)) && (unsigned)(v[i] >> 32) == tagexp){
            h_lds[e0i + (i<<6)] = __uint_as_float((unsigned)v[i]);
            fresh |= (1u<<i);
          }
        }
        if (++rounds > 16384) break;           // anti-hang guard
      }
    }
    __syncthreads();

    // ---- dot products: 8 gate rows (this wave's gate) + redundant W_out rows ----
    float ga[8];
    #pragma unroll
    for (int u = 0; u < 8; ++u) ga[u] = 0.f;
    float r0 = 0.f, r1 = 0.f;
    #pragma unroll
    for (int i = 0; i < 16; ++i){
      const float2 hv = *(const float2*)(h_lds + 2*l + 128*i);
      r0 = fmaf(wo0[i].x, hv.x, r0); r0 = fmaf(wo0[i].y, hv.y, r0);
      r1 = fmaf(wo1[i].x, hv.x, r1); r1 = fmaf(wo1[i].y, hv.y, r1);
      #pragma unroll
      for (int u = 0; u < 8; ++u){
        ga[u] = fmaf(whh[u][i].x, hv.x, ga[u]);
        ga[u] = fmaf(whh[u][i].y, hv.y, ga[u]);
      }
    }
    #pragma unroll
    for (int u = 0; u < 8; ++u) ga[u] = wred(ga[u]);
    r0 = wred(r0); r1 = wred(r1);

    // ---- raw_{t-1}, teacher forcing (loss handled by separate kernel) ----
    const float raw0 = r0 + bo0, raw1 = r1 + bo1;
    float n0, n1;
    if (t == 0){ n0 = 1.f; n1 = 1.f; }     // x0 = W_emb@ones(2)+b_emb  <=> nxt=(1,1)
    else {
      if (wgid == 0 && tid == 0){
        out[2*(t-1)]   = raw0;
        out[2*(t-1)+1] = raw1;
      }
      n0 = (ug == 1) ? g0 : raw0;
      n1 = (ug == 1) ? g1 : raw1;
    }

    // ---- finalize this wave's gate values for its 8 units ----
    if (l < 8){
      float gate = ga[0];
      #pragma unroll
      for (int u = 1; u < 8; ++u) if (l == u) gate = ga[u];
      gate += fmaf(myE0, n0, fmaf(myE1, n1, myB));
      gates_lds[gw][l] = gate;
    }
    __syncthreads();

    // ---- LSTM cell (wave0 lanes 0..7): publish tagged h_new, fire-and-forget ----
    if (gw == 0 && l < 8){
      const float gi = gates_lds[0][l], gf = gates_lds[1][l];
      const float gg = gates_lds[2][l], go = gates_lds[3][l];
      const float cn = sigm(gf)*c_state + sigm(gi)*tanhf(gg);
      const float hn = sigm(go)*tanhf(cn);
      c_state = cn;
      const unsigned long long pk =
          ((unsigned long long)(unsigned)(t + 1) << 32) |
          (unsigned long long)__float_as_uint(hn);
      __hip_atomic_store(hbuf + (t&1)*HH + j0 + l, pk, __ATOMIC_RELAXED, __HIP_MEMORY_SCOPE_AGENT);
    }
  }

  if (wgid != 0) return;

  // ---------- epilogue (WG0): raw for the final step ----------
  {
    const int e0i = (gw << 9) + l;
    const unsigned long long* bp = hbuf + ((TT-1)&1)*HH + e0i;
    const unsigned tagexp = (unsigned)TT;
    unsigned fresh = 0; int rounds = 0;
    while (fresh != 0xFFu){
      unsigned long long v[8];
      #pragma unroll
      for (int i = 0; i < 8; ++i)
        v[i] = __hip_atomic_load(bp + (i<<6), __ATOMIC_RELAXED, __HIP_MEMORY_SCOPE_AGENT);
      #pragma unroll
      for (int i = 0; i < 8; ++i){
        if (!(fresh & (1u<<i)) && (unsigned)(v[i] >> 32) == tagexp){
          h_lds[e0i + (i<<6)] = __uint_as_float((unsigned)v[i]);
          fresh |= (1u<<i);
        }
      }
      if (++rounds > 16384) break;
    }
  }
  __syncthreads();
  if (gw == 0){
    float r0 = 0.f, r1 = 0.f;
    #pragma unroll
    for (int i = 0; i < 16; ++i){
      const float2 hv = *(const float2*)(h_lds + 2*l + 128*i);
      r0 = fmaf(wo0[i].x, hv.x, r0); r0 = fmaf(wo0[i].y, hv.y, r0);
      r1 = fmaf(wo1[i].x, hv.x, r1); r1 = fmaf(wo1[i].y, hv.y, r1);
    }
    r0 = wred(r0); r1 = wred(r1);
    if (l == 0){
      out[2*(TT-1)]   = r0 + bo0;
      out[2*(TT-1)+1] = r1 + bo1;
    }
  }
}

// Loss = pure function of (preds, gt) — computed from the validated preds buffer.
extern "C" __global__ void loss_kernel(const float* __restrict__ preds,
                                       const float* __restrict__ gt,
                                       float* __restrict__ loss_out)
{
  const int tid = threadIdx.x;   // 256 threads, 8 steps each
  float acc = 0.f;
  #pragma unroll
  for (int s = 0; s < 8; ++s){
    const int t = tid + 256*s;
    const float d0 = preds[2*t]   - gt[2*t];
    const float d1 = preds[2*t+1] - gt[2*t+1];
    acc += 0.5f*(d0*d0 + d1*d1);
  }
  acc = wred(acc);
  __shared__ float ws[4];
  if ((tid & 63) == 0) ws[tid >> 6] = acc;
  __syncthreads();
  if (tid == 0) loss_out[0] = ws[0] + ws[1] + ws[2] + ws[3];
}

extern "C" void kernel_launch(void* const* d_in, const int* in_sizes, int n_in,
                              void* d_out, int out_size, void* d_ws, size_t ws_size,
                              hipStream_t stream)
{
  (void)in_sizes; (void)n_in; (void)out_size; (void)ws_size;
  const float* h0    = (const float*)d_in[0];
  const float* c0    = (const float*)d_in[1];
  const float* gt    = (const float*)d_in[2];
  const int*   ugt   = (const int*)  d_in[3];
  const float* W_emb = (const float*)d_in[4];
  const float* b_emb = (const float*)d_in[5];
  const float* W_ih  = (const float*)d_in[6];
  const float* b_ih  = (const float*)d_in[7];
  const float* W_hh  = (const float*)d_in[8];
  const float* b_hh  = (const float*)d_in[9];
  const float* W_out = (const float*)d_in[10];
  const float* b_out = (const float*)d_in[11];
  float* out  = (float*)d_out;
  unsigned long long* hbuf = (unsigned long long*)d_ws;   // 2 x 2048 tagged entries (32 KB)

  void* args[] = { &h0, &c0, &gt, &ugt, &W_emb, &b_emb, &W_ih, &b_ih,
                   &W_hh, &b_hh, &W_out, &b_out, &out, &hbuf };
  hipLaunchCooperativeKernel((const void*)lstm_seq_kernel,
                             dim3(NWG), dim3(NTHR), args, 0, stream);

  loss_kernel<<<dim3(1), dim3(NTHR), 0, stream>>>(out, gt, out + 2*TT);
}

// Round 9
// 9109.591 us; speedup vs baseline: 2.7908x; 1.0490x over previous
//
#include <hip/hip_runtime.h>

#define NWG   256
#define NTHR  256
#define TT    2048
#define HH    2048
#define EE    1024

__device__ __forceinline__ float wred(float v){
  v += __shfl_xor(v, 1, 64);
  v += __shfl_xor(v, 2, 64);
  v += __shfl_xor(v, 4, 64);
  v += __shfl_xor(v, 8, 64);
  v += __shfl_xor(v, 16, 64);
  v += __shfl_xor(v, 32, 64);
  return v;
}

__device__ __forceinline__ float sigm(float x){ return 1.0f / (1.0f + __expf(-x)); }

extern "C" __global__ void __launch_bounds__(NTHR, 1)
lstm_seq_kernel(const float* __restrict__ h0, const float* __restrict__ c0,
                const float* __restrict__ gt, const int* __restrict__ ugt,
                const float* __restrict__ W_emb, const float* __restrict__ b_emb,
                const float* __restrict__ W_ih, const float* __restrict__ b_ih,
                const float* __restrict__ W_hh, const float* __restrict__ b_hh,
                const float* __restrict__ W_out, const float* __restrict__ b_out,
                float* __restrict__ out, unsigned long long* __restrict__ hbuf)
{
  const int wgid = blockIdx.x;    // 0..255, owns hidden units [8*wgid, 8*wgid+8)
  const int tid  = threadIdx.x;
  const int gw   = tid >> 6;      // wave owns units uA=j0+2gw, uB=uA+1 (ALL 4 gates)
  const int l    = tid & 63;
  const int j0   = wgid * 8;
  const int uA   = j0 + 2*gw;

  __shared__ float h_lds[2][HH];  // double-buffered: one barrier/step, waves may skew

  // ---------- setup: W_hh rows for this wave's 2 units x 4 gates ----------
  // u = g*2 + b  (g: 0=i,1=f,2=g,3=o ; b: 0=unit A, 1=unit B), row = 2048*g + uA + b
  float2 whh[8][16];
  #pragma unroll
  for (int u = 0; u < 8; ++u){
    const float* rp = W_hh + (size_t)(2048*(u>>1) + uA + (u&1)) * HH;
    #pragma unroll
    for (int i = 0; i < 16; ++i)
      whh[u][i] = *(const float2*)(rp + 2*l + 128*i);
  }
  // W_out rows (each wave keeps a copy -> redundant raw, no cross-wave exchange)
  float2 wo0[16], wo1[16];
  #pragma unroll
  for (int i = 0; i < 16; ++i){
    wo0[i] = *(const float2*)(W_out + 2*l + 128*i);
    wo1[i] = *(const float2*)(W_out + HH + 2*l + 128*i);
  }
  const float bo0 = b_out[0], bo1 = b_out[1];

  // ---------- setup: E = W_ih@W_emb cols, B = W_ih@b_emb + b_ih + b_hh ----------
  // Replicated in ALL lanes (wred broadcasts) so the cell can run wave-redundant.
  float aE0[8], aE1[8], aB[8];
  #pragma unroll
  for (int u = 0; u < 8; ++u){ aE0[u] = 0.f; aE1[u] = 0.f; aB[u] = 0.f; }
  for (int i = 0; i < 16; ++i){
    const int k = l + 64*i;
    const float2 we = *(const float2*)(W_emb + 2*k);
    const float be = b_emb[k];
    #pragma unroll
    for (int u = 0; u < 8; ++u){
      const float wv = W_ih[(size_t)(2048*(u>>1) + uA + (u&1))*EE + k];
      aE0[u] = fmaf(wv, we.x, aE0[u]);
      aE1[u] = fmaf(wv, we.y, aE1[u]);
      aB[u]  = fmaf(wv, be,  aB[u]);
    }
  }
  float e0v[8], e1v[8], bv[8];
  #pragma unroll
  for (int u = 0; u < 8; ++u){
    const int r = 2048*(u>>1) + uA + (u&1);
    e0v[u] = wred(aE0[u]);
    e1v[u] = wred(aE1[u]);
    bv[u]  = wred(aB[u]) + b_ih[r] + b_hh[r];
  }

  float cA = c0[uA], cB = c0[uA + 1];   // all lanes hold both cell states

  for (int t = 0; t < TT; ++t){
    // ---- hoist gt/ugt for this step (cached loads, overlap the poll) ----
    float g0 = 0.f, g1 = 0.f; int ug = 0;
    if (t > 0){
      g0 = gt[2*(t-1)]; g1 = gt[2*(t-1)+1]; ug = ugt[t-1];
    }

    // ---- poll tagged h_{t-1} and stage into LDS buffer t&1 ----
    float* hl = h_lds[t & 1];
    const int e0i = (gw << 9) + l;              // this wave's quarter
    if (t == 0){
      #pragma unroll
      for (int i = 0; i < 8; ++i)
        hl[e0i + (i<<6)] = h0[e0i + (i<<6)];
    } else {
      const unsigned long long* bp = hbuf + ((t-1)&1)*HH + e0i;
      const unsigned tagexp = (unsigned)t;
      unsigned fresh = 0; int rounds = 0;
      while (fresh != 0xFFu){
        unsigned long long v[8];
        #pragma unroll
        for (int i = 0; i < 8; ++i)
          v[i] = __hip_atomic_load(bp + (i<<6), __ATOMIC_RELAXED, __HIP_MEMORY_SCOPE_AGENT);
        #pragma unroll
        for (int i = 0; i < 8; ++i){
          if (!(fresh & (1u<<i)) && (unsigned)(v[i] >> 32) == tagexp){
            hl[e0i + (i<<6)] = __uint_as_float((unsigned)v[i]);
            fresh |= (1u<<i);
          }
        }
        if (++rounds > 16384) break;           // anti-hang guard
      }
    }
    __syncthreads();   // the ONLY barrier per step (staging rendezvous)

    // ---- dot products: 8 rows (2 units x 4 gates) + redundant W_out rows ----
    float ga[8];
    #pragma unroll
    for (int u = 0; u < 8; ++u) ga[u] = 0.f;
    float r0 = 0.f, r1 = 0.f;
    #pragma unroll
    for (int i = 0; i < 16; ++i){
      const float2 hv = *(const float2*)(hl + 2*l + 128*i);
      r0 = fmaf(wo0[i].x, hv.x, r0); r0 = fmaf(wo0[i].y, hv.y, r0);
      r1 = fmaf(wo1[i].x, hv.x, r1); r1 = fmaf(wo1[i].y, hv.y, r1);
      #pragma unroll
      for (int u = 0; u < 8; ++u){
        ga[u] = fmaf(whh[u][i].x, hv.x, ga[u]);
        ga[u] = fmaf(whh[u][i].y, hv.y, ga[u]);
      }
    }
    #pragma unroll
    for (int u = 0; u < 8; ++u) ga[u] = wred(ga[u]);   // sums land in ALL lanes
    r0 = wred(r0); r1 = wred(r1);

    // ---- raw_{t-1}, teacher forcing ----
    const float raw0 = r0 + bo0, raw1 = r1 + bo1;
    float n0, n1;
    if (t == 0){ n0 = 1.f; n1 = 1.f; }     // x0 = W_emb@ones(2)+b_emb  <=> nxt=(1,1)
    else {
      if (wgid == 0 && tid == 0){
        out[2*(t-1)]   = raw0;
        out[2*(t-1)+1] = raw1;
      }
      n0 = (ug == 1) ? g0 : raw0;
      n1 = (ug == 1) ? g1 : raw1;
    }

    // ---- gate finals + LSTM cells, wave-redundant in all lanes ----
    float gf[8];
    #pragma unroll
    for (int u = 0; u < 8; ++u)
      gf[u] = ga[u] + fmaf(e0v[u], n0, fmaf(e1v[u], n1, bv[u]));
    const float cAn = sigm(gf[2])*cA + sigm(gf[0])*tanhf(gf[4]);
    const float hA  = sigm(gf[6])*tanhf(cAn); cA = cAn;
    const float cBn = sigm(gf[3])*cB + sigm(gf[1])*tanhf(gf[5]);
    const float hB  = sigm(gf[7])*tanhf(cBn); cB = cBn;

    // ---- per-wave publish (no second barrier, no wave0 bottleneck) ----
    if (l < 2){
      const float hv = (l == 0) ? hA : hB;
      const unsigned long long pk =
          ((unsigned long long)(unsigned)(t + 1) << 32) |
          (unsigned long long)__float_as_uint(hv);
      __hip_atomic_store(hbuf + (t&1)*HH + uA + l, pk, __ATOMIC_RELAXED, __HIP_MEMORY_SCOPE_AGENT);
    }
  }

  if (wgid != 0) return;

  // ---------- epilogue (WG0): raw for the final step ----------
  {
    float* hl = h_lds[0];
    const int e0i = (gw << 9) + l;
    const unsigned long long* bp = hbuf + ((TT-1)&1)*HH + e0i;
    const unsigned tagexp = (unsigned)TT;
    unsigned fresh = 0; int rounds = 0;
    while (fresh != 0xFFu){
      unsigned long long v[8];
      #pragma unroll
      for (int i = 0; i < 8; ++i)
        v[i] = __hip_atomic_load(bp + (i<<6), __ATOMIC_RELAXED, __HIP_MEMORY_SCOPE_AGENT);
      #pragma unroll
      for (int i = 0; i < 8; ++i){
        if (!(fresh & (1u<<i)) && (unsigned)(v[i] >> 32) == tagexp){
          hl[e0i + (i<<6)] = __uint_as_float((unsigned)v[i]);
          fresh |= (1u<<i);
        }
      }
      if (++rounds > 16384) break;
    }
  }
  __syncthreads();
  if (gw == 0){
    const float* hl = h_lds[0];
    float r0 = 0.f, r1 = 0.f;
    #pragma unroll
    for (int i = 0; i < 16; ++i){
      const float2 hv = *(const float2*)(hl + 2*l + 128*i);
      r0 = fmaf(wo0[i].x, hv.x, r0); r0 = fmaf(wo0[i].y, hv.y, r0);
      r1 = fmaf(wo1[i].x, hv.x, r1); r1 = fmaf(wo1[i].y, hv.y, r1);
    }
    r0 = wred(r0); r1 = wred(r1);
    if (l == 0){
      out[2*(TT-1)]   = r0 + bo0;
      out[2*(TT-1)+1] = r1 + bo1;
    }
  }
}

// Loss = pure function of (preds, gt) — computed from the validated preds buffer.
extern "C" __global__ void loss_kernel(const float* __restrict__ preds,
                                       const float* __restrict__ gt,
                                       float* __restrict__ loss_out)
{
  const int tid = threadIdx.x;   // 256 threads, 8 steps each
  float acc = 0.f;
  #pragma unroll
  for (int s = 0; s < 8; ++s){
    const int t = tid + 256*s;
    const float d0 = preds[2*t]   - gt[2*t];
    const float d1 = preds[2*t+1] - gt[2*t+1];
    acc += 0.5f*(d0*d0 + d1*d1);
  }
  acc = wred(acc);
  __shared__ float ws[4];
  if ((tid & 63) == 0) ws[tid >> 6] = acc;
  __syncthreads();
  if (tid == 0) loss_out[0] = ws[0] + ws[1] + ws[2] + ws[3];
}

extern "C" void kernel_launch(void* const* d_in, const int* in_sizes, int n_in,
                              void* d_out, int out_size, void* d_ws, size_t ws_size,
                              hipStream_t stream)
{
  (void)in_sizes; (void)n_in; (void)out_size; (void)ws_size;
  const float* h0    = (const float*)d_in[0];
  const float* c0    = (const float*)d_in[1];
  const float* gt    = (const float*)d_in[2];
  const int*   ugt   = (const int*)  d_in[3];
  const float* W_emb = (const float*)d_in[4];
  const float* b_emb = (const float*)d_in[5];
  const float* W_ih  = (const float*)d_in[6];
  const float* b_ih  = (const float*)d_in[7];
  const float* W_hh  = (const float*)d_in[8];
  const float* b_hh  = (const float*)d_in[9];
  const float* W_out = (const float*)d_in[10];
  const float* b_out = (const float*)d_in[11];
  float* out  = (float*)d_out;
  unsigned long long* hbuf = (unsigned long long*)d_ws;   // 2 x 2048 tagged entries (32 KB)

  void* args[] = { &h0, &c0, &gt, &ugt, &W_emb, &b_emb, &W_ih, &b_ih,
                   &W_hh, &b_hh, &W_out, &b_out, &out, &hbuf };
  hipLaunchCooperativeKernel((const void*)lstm_seq_kernel,
                             dim3(NWG), dim3(NTHR), args, 0, stream);

  loss_kernel<<<dim3(1), dim3(NTHR), 0, stream>>>(out, gt, out + 2*TT);
}